// Round 8
// baseline (658.443 us; speedup 1.0000x reference)
//
#include <hip/hip_runtime.h>
#include <math.h>

#define BB 128
#define SS 2048
#define HH 64
#define EPSQ 1e-10f
#define NT ((size_t)BB * SS * HH)

typedef float f2 __attribute__((ext_vector_type(2)));
typedef float f4 __attribute__((ext_vector_type(4)));

// ---- ws layout ----
// 0      : Qn[64][64]  Qn[i][j] = softmax(base)[i][j] + EPS  (natural, 16 KB)
// 16384  : D[64]       softmax(init)+EPS                     (256 B)

__global__ __launch_bounds__(64) void hmm_setup(const float* __restrict__ base,
                                                const float* __restrict__ init,
                                                float* __restrict__ Qn,
                                                float* __restrict__ D) {
    const int i = threadIdx.x;  // 0..63 = source state (row)
    float mx = -INFINITY;
    for (int k = 0; k < HH; ++k) mx = fmaxf(mx, base[i * HH + k]);
    float z = 0.f;
    for (int k = 0; k < HH; ++k) z += expf(base[i * HH + k] - mx);
    float invz = 1.f / z;
    for (int k = 0; k < HH; ++k) Qn[i * HH + k] = expf(base[i * HH + k] - mx) * invz + EPSQ;
    float x = init[i];
    float m2 = x;
    for (int d = 1; d < 64; d <<= 1) m2 = fmaxf(m2, __shfl_xor(m2, d, 64));
    float e = expf(x - m2);
    float zz = e;
    for (int d = 1; d < 64; d <<= 1) zz += __shfl_xor(zz, d, 64);
    D[i] = e / zz + EPSQ;
}

// em(x) for a state: c0 + sum_c (a_c + q_c*x_c)*x_c
__device__ __forceinline__ float emv(const f4 x, const f4 a, const f4 q, float c0) {
    float em = c0;
    em = fmaf(fmaf(q.x, x.x, a.x), x.x, em);
    em = fmaf(fmaf(q.y, x.y, a.y), x.y, em);
    em = fmaf(fmaf(q.z, x.z, a.z), x.z, em);
    em = fmaf(fmaf(q.w, x.w, a.w), x.w, em);
    return em;
}

// Plain packed f32 ops (no op_sel — the exact form validated in R5).
#define PK_MUL(d, a, b) asm("v_pk_mul_f32 %0, %1, %2" : "=v"(d) : "v"(a), "v"(b))
#define PK_FMA(d, a, b) asm("v_pk_fma_f32 %0, %1, %2, %0" : "+v"(d) : "v"(a), "v"(b))

// quad_perm butterfly add on an f2 (both 32-bit halves)
#define DPPADD(v, CTRL)                                                              \
    {                                                                                \
        int _a = __builtin_amdgcn_mov_dpp(__float_as_int(v.x), CTRL, 0xF, 0xF, true); \
        int _b = __builtin_amdgcn_mov_dpp(__float_as_int(v.y), CTRL, 0xF, 0xF, true); \
        v.x += __int_as_float(_a);                                                   \
        v.y += __int_as_float(_b);                                                   \
    }

#define LO2(v) __builtin_shufflevector(v, v, 0, 1)
#define HI2(v) __builtin_shufflevector(v, v, 2, 3)

// One wave per batch. Lane l = (g = l>>2, s = l&3): computes outputs 4g..4g+3
// over sources 16s..16s+15. Pairwise-packed dot: uu[m] = {U[i0+2m],U[i0+2m+1]}
// (free f2 halves of 4 ds_read_b128), Q pre-transposed so acc_j += qj[j][m] *
// uu[m] is a plain elementwise v_pk_fma_f32; horizontal add per output, then a
// 2-stage quad_perm DPP butterfly combines the 4 source-quarters. Per-lane LDS
// demand is 16 U values (64 B) vs 256 B for full broadcast. Emission E[j] is
// computed one step ahead (state=lane) and redistributed via a 256 B LDS
// buffer. Renorm g_t = rcp(U_{t-1}[0]) delayed; alpha stored fused (A + log).
// Single wave => in-order DS, zero barriers.
__global__ __launch_bounds__(64, 1) void hmm_scan(const float* __restrict__ obs,
                                                  const float* __restrict__ means,
                                                  const float* __restrict__ logvars,
                                                  const float* __restrict__ Qn,
                                                  const float* __restrict__ D,
                                                  float* __restrict__ out) {
    const int b = blockIdx.x;
    const int l = threadIdx.x;  // 0..63
    const int g = l >> 2;       // output group: states 4g..4g+3
    const int s = l & 3;        // source quarter: states 16s..16s+15
    const bool b0 = (l & 1) != 0;
    const bool b1 = (l & 2) != 0;

    __shared__ f4 OBS[SS];          // 32 KB
    __shared__ float U_lds[HH];     // 256 B
    __shared__ float E_lds[HH];     // 256 B

    // stage obs (coalesced b128; single wave => no barrier)
    const f4* obs4 = (const f4*)obs + (size_t)b * SS;
#pragma unroll 8
    for (int t = l; t < SS; t += 64) OBS[t] = obs4[t];

    // Q fragment, pre-transposed for pairwise-packed dot (prologue-only cost):
    // qj[j][m] = {Qn[16s+2m][4g+j], Qn[16s+2m+1][4g+j]}   (32 f2 = 64 VGPR)
    f2 q0[8], q1[8], q2[8], q3[8];
    const float* qbase = Qn + (size_t)(16 * s) * HH + 4 * g;
#pragma unroll
    for (int m = 0; m < 8; ++m) {
        f4 rA = *(const f4*)(qbase + (size_t)(2 * m) * HH);
        f4 rB = *(const f4*)(qbase + (size_t)(2 * m + 1) * HH);
        q0[m] = (f2){rA.x, rB.x};
        q1[m] = (f2){rA.y, rB.y};
        q2[m] = (f2){rA.z, rB.z};
        q3[m] = (f2){rA.w, rB.w};
    }

    // emission constants for state l
    const f4 mu = ((const f4*)means)[l];
    const f4 lv = ((const f4*)logvars)[l];
    f4 ea, eq;
    float ec = 0.f;
    {
        float v0 = __expf(lv.x) + 1e-6f, v1 = __expf(lv.y) + 1e-6f;
        float v2 = __expf(lv.z) + 1e-6f, v3 = __expf(lv.w) + 1e-6f;
        float i0 = 1.f / v0, i1 = 1.f / v1, i2 = 1.f / v2, i3 = 1.f / v3;
        ea.x = mu.x * i0; ea.y = mu.y * i1; ea.z = mu.z * i2; ea.w = mu.w * i3;
        eq.x = -0.5f * i0; eq.y = -0.5f * i1; eq.z = -0.5f * i2; eq.w = -0.5f * i3;
        ec += logf(6.2831853071795864f * v0) + mu.x * mu.x * i0;
        ec += logf(6.2831853071795864f * v1) + mu.y * mu.y * i1;
        ec += logf(6.2831853071795864f * v2) + mu.z * mu.z * i2;
        ec += logf(6.2831853071795864f * v3) + mu.w * mu.w * i3;
        ec = -0.5f * ec;
    }

    float* alpha_b = out + (size_t)b * SS * HH;

    // ---- t = 0 (state = lane layout) ----
    float u0 = D[l] * __expf(emv(OBS[0], ea, eq, ec));
    U_lds[l] = u0;                       // b32 x64
    alpha_b[l] = __logf(u0);             // A_0 = 0
    E_lds[l] = __expf(emv(OBS[1], ea, eq, ec));  // E for step 1
    float A = 0.f;
    float gcur = __builtin_amdgcn_rcpf(__int_as_float(
        __builtin_amdgcn_readfirstlane(__float_as_int(u0))));

    f4 un;
#pragma unroll 2
    for (int t = 1; t < SS; ++t) {
        // ---- loads first (in-order DS; true deps on prev step's writes) ----
        const f4* Uq = (const f4*)U_lds + 4 * s;  // floats 16s..16s+15
        f4 U0 = Uq[0], U1 = Uq[1], U2 = Uq[2], U3 = Uq[3];
        f4 e4 = *(const f4*)(E_lds + 4 * g);

        // ---- uniform prep (off the dot's critical path) ----
        A -= __logf(gcur);
        const float gE0 = gcur * e4.x, gE1 = gcur * e4.y;
        const float gE2 = gcur * e4.z, gE3 = gcur * e4.w;

        // ---- dot: 4 outputs x 16 sources, pairwise-packed (no op_sel) ----
        f2 uu0 = LO2(U0), uu1 = HI2(U0), uu2 = LO2(U1), uu3 = HI2(U1);
        f2 uu4 = LO2(U2), uu5 = HI2(U2), uu6 = LO2(U3), uu7 = HI2(U3);
        f2 acc0, acc1, acc2, acc3;
        PK_MUL(acc0, q0[0], uu0); PK_MUL(acc1, q1[0], uu0);
        PK_MUL(acc2, q2[0], uu0); PK_MUL(acc3, q3[0], uu0);
        PK_FMA(acc0, q0[1], uu1); PK_FMA(acc1, q1[1], uu1);
        PK_FMA(acc2, q2[1], uu1); PK_FMA(acc3, q3[1], uu1);
        PK_FMA(acc0, q0[2], uu2); PK_FMA(acc1, q1[2], uu2);
        PK_FMA(acc2, q2[2], uu2); PK_FMA(acc3, q3[2], uu2);
        PK_FMA(acc0, q0[3], uu3); PK_FMA(acc1, q1[3], uu3);
        PK_FMA(acc2, q2[3], uu3); PK_FMA(acc3, q3[3], uu3);
        PK_FMA(acc0, q0[4], uu4); PK_FMA(acc1, q1[4], uu4);
        PK_FMA(acc2, q2[4], uu4); PK_FMA(acc3, q3[4], uu4);
        PK_FMA(acc0, q0[5], uu5); PK_FMA(acc1, q1[5], uu5);
        PK_FMA(acc2, q2[5], uu5); PK_FMA(acc3, q3[5], uu5);
        PK_FMA(acc0, q0[6], uu6); PK_FMA(acc1, q1[6], uu6);
        PK_FMA(acc2, q2[6], uu6); PK_FMA(acc3, q3[6], uu6);
        PK_FMA(acc0, q0[7], uu7); PK_FMA(acc1, q1[7], uu7);
        PK_FMA(acc2, q2[7], uu7); PK_FMA(acc3, q3[7], uu7);

        // horizontal within pairs, then quad butterfly over source-quarters
        f2 sA = (f2){acc0.x + acc0.y, acc1.x + acc1.y};
        f2 sB = (f2){acc2.x + acc2.y, acc3.x + acc3.y};
        DPPADD(sA, 0xB1); DPPADD(sB, 0xB1);
        DPPADD(sA, 0x4E); DPPADD(sB, 0x4E);

        un.x = sA.x * gE0;
        un.y = sA.y * gE1;
        un.z = sB.x * gE2;
        un.w = sB.y * gE3;

        // quad leader writes the group's new U (16 lanes, b128, 256 B)
        if ((l & 3) == 0) *(f4*)(U_lds + 4 * g) = un;

        // alpha: every lane stores its own state (component l&3 of its group)
        const float usel = b1 ? (b0 ? un.w : un.z) : (b0 ? un.y : un.x);
        alpha_b[(size_t)t * HH + l] = A + __logf(usel);

        // next step's renorm scale (uniform; off-path)
        gcur = __builtin_amdgcn_rcpf(__int_as_float(
            __builtin_amdgcn_readfirstlane(__float_as_int(un.x))));

        // next step's emission (state = lane), redistributed via LDS
        const int tn = (t < SS - 1) ? t + 1 : SS - 1;
        const f4 xn = OBS[tn];
        E_lds[l] = __expf(emv(xn, ea, eq, ec));
    }

    // log-likelihood: lane l holds un for group g; reduce distinct groups
    float tot = (un.x + un.y) + (un.z + un.w);
    tot += __shfl_xor(tot, 4, 64);
    tot += __shfl_xor(tot, 8, 64);
    tot += __shfl_xor(tot, 16, 64);
    tot += __shfl_xor(tot, 32, 64);
    if (l == 0) out[NT + b] = A + __logf(tot);
}

extern "C" void kernel_launch(void* const* d_in, const int* in_sizes, int n_in,
                              void* d_out, int out_size, void* d_ws, size_t ws_size,
                              hipStream_t stream) {
    (void)in_sizes; (void)n_in; (void)out_size; (void)ws_size;
    const float* obs     = (const float*)d_in[0];
    const float* base    = (const float*)d_in[1];
    const float* init    = (const float*)d_in[2];
    const float* means   = (const float*)d_in[3];
    const float* logvars = (const float*)d_in[4];
    float* out = (float*)d_out;

    float* Qn = (float*)d_ws;                   // 16 KB
    float* D  = (float*)((char*)d_ws + 16384);  // 256 B

    hmm_setup<<<1, 64, 0, stream>>>(base, init, Qn, D);
    hmm_scan<<<BB, 64, 0, stream>>>(obs, means, logvars, Qn, D, out);
}

// Round 9
// 471.926 us; speedup vs baseline: 1.3952x; 1.3952x over previous
//
#include <hip/hip_runtime.h>
#include <math.h>

#define BB 128
#define SS 2048
#define HH 64
#define EPSQ 1e-10f
#define NT ((size_t)BB * SS * HH)

typedef float f2 __attribute__((ext_vector_type(2)));
typedef float f4 __attribute__((ext_vector_type(4)));

// ---- ws layout ----
// 0      : Qt[64][64]  Qt[j][i] = softmax(base)[i][j] + EPS  (transposed, 16 KB)
// 16384  : D[64]       softmax(init)+EPS                     (256 B)

__global__ __launch_bounds__(64) void hmm_setup(const float* __restrict__ base,
                                                const float* __restrict__ init,
                                                float* __restrict__ Qt,
                                                float* __restrict__ D) {
    const int i = threadIdx.x;  // 0..63 = source state (row of base)
    float mx = -INFINITY;
    for (int k = 0; k < HH; ++k) mx = fmaxf(mx, base[i * HH + k]);
    float z = 0.f;
    for (int k = 0; k < HH; ++k) z += expf(base[i * HH + k] - mx);
    float invz = 1.f / z;
    for (int k = 0; k < HH; ++k) Qt[k * HH + i] = expf(base[i * HH + k] - mx) * invz + EPSQ;
    float x = init[i];
    float m2 = x;
    for (int d = 1; d < 64; d <<= 1) m2 = fmaxf(m2, __shfl_xor(m2, d, 64));
    float e = expf(x - m2);
    float zz = e;
    for (int d = 1; d < 64; d <<= 1) zz += __shfl_xor(zz, d, 64);
    D[i] = e / zz + EPSQ;
}

// em(x) for a state: c0 + sum_c (a_c + q_c*x_c)*x_c
__device__ __forceinline__ float emv(const f4 x, const f4 a, const f4 q, float c0) {
    float em = c0;
    em = fmaf(fmaf(q.x, x.x, a.x), x.x, em);
    em = fmaf(fmaf(q.y, x.y, a.y), x.y, em);
    em = fmaf(fmaf(q.z, x.z, a.z), x.z, em);
    em = fmaf(fmaf(q.w, x.w, a.w), x.w, em);
    return em;
}

// Plain packed f32 ops (validated in R5). No op_sel (R7's failure mode).
#define PK_MUL(d, a, b) asm("v_pk_mul_f32 %0, %1, %2" : "=v"(d) : "v"(a), "v"(b))
#define PK_FMA(d, a, b) asm("v_pk_fma_f32 %0, %1, %2, %0" : "+v"(d) : "v"(a), "v"(b))
#define PK_ADD(d, a, b) asm("v_pk_add_f32 %0, %1, %2" : "=v"(d) : "v"(a), "v"(b))

// single-stage quad_perm [1,0,3,2] (lane ^= 1) add — validated in R1
#define DPP_X1_ADD(s)                                                                  \
    {                                                                                  \
        int _v = __builtin_amdgcn_mov_dpp(__float_as_int(s), 0xB1, 0xF, 0xF, true);    \
        s += __int_as_float(_v);                                                       \
    }

#define LO2(v) __builtin_shufflevector(v, v, 0, 1)
#define HI2(v) __builtin_shufflevector(v, v, 2, 3)

#define RFL(x) __int_as_float(__builtin_amdgcn_readfirstlane(__float_as_int(x)))

// One wave per batch; lane l owns state l. Pair-split dot: parity p = l&1
// selects source half [32p, 32p+32); lane computes partial dots for BOTH
// outputs of its pair {e, e+1} (e = l&~1) over its half: 32 pk ops (the
// algorithmic floor), 8 ds_read_b128 (half the broadcast traffic), one
// DPP xor-1 add + one cndmask to combine. Renorm g_t = rcp(U[0]) delayed one
// step; emission exp computed one step ahead; alpha = A + log(U) stored
// fused; A propagated by readfirstlane of lane-0's stored alpha (no extra
// log). Single wave => in-order DS, zero barriers, single U buffer.
__global__ __launch_bounds__(64, 1) void hmm_scan(const float* __restrict__ obs,
                                                  const float* __restrict__ means,
                                                  const float* __restrict__ logvars,
                                                  const float* __restrict__ Qt,
                                                  const float* __restrict__ D,
                                                  float* __restrict__ out) {
    const int b = blockIdx.x;
    const int l = threadIdx.x;  // 0..63 = state
    const int p = l & 1;        // source-half parity
    const int e = l & ~1;       // even output of my pair

    __shared__ f4 OBS[SS];       // 32 KB
    __shared__ float U_lds[HH];  // 256 B, single buffer (in-order DS)

    // stage obs (coalesced b128; single wave => no barrier)
    const f4* obs4 = (const f4*)obs + (size_t)b * SS;
#pragma unroll 8
    for (int t = l; t < SS; t += 64) OBS[t] = obs4[t];

    // Q fragments: QA[k] = Qt[e][32p+4k .. +3], QB[k] = Qt[e+1][32p+4k .. +3]
    // (Qt row j = column j of Q). 16 f4 = 64 VGPRs.
    f4 QA[8], QB[8];
    {
        const f4* qa = (const f4*)(Qt + (size_t)e * HH + 32 * p);
        const f4* qb = (const f4*)(Qt + (size_t)(e + 1) * HH + 32 * p);
#pragma unroll
        for (int k = 0; k < 8; ++k) { QA[k] = qa[k]; QB[k] = qb[k]; }
    }

    // emission constants for state l
    const f4 mu = ((const f4*)means)[l];
    const f4 lv = ((const f4*)logvars)[l];
    f4 ea, eq;
    float ec = 0.f;
    {
        float v0 = __expf(lv.x) + 1e-6f, v1 = __expf(lv.y) + 1e-6f;
        float v2 = __expf(lv.z) + 1e-6f, v3 = __expf(lv.w) + 1e-6f;
        float i0 = 1.f / v0, i1 = 1.f / v1, i2 = 1.f / v2, i3 = 1.f / v3;
        ea.x = mu.x * i0; ea.y = mu.y * i1; ea.z = mu.z * i2; ea.w = mu.w * i3;
        eq.x = -0.5f * i0; eq.y = -0.5f * i1; eq.z = -0.5f * i2; eq.w = -0.5f * i3;
        ec += logf(6.2831853071795864f * v0) + mu.x * mu.x * i0;
        ec += logf(6.2831853071795864f * v1) + mu.y * mu.y * i1;
        ec += logf(6.2831853071795864f * v2) + mu.z * mu.z * i2;
        ec += logf(6.2831853071795864f * v3) + mu.w * mu.w * i3;
        ec = -0.5f * ec;
    }

    float* alpha_b = out + (size_t)b * SS * HH;

    // ---- t = 0 ----
    float u = D[l] * __expf(emv(OBS[0], ea, eq, ec));
    U_lds[l] = u;
    float lg = __logf(u);
    alpha_b[l] = lg;              // A_0 = 0
    float A = RFL(lg);            // = A_1 = log(U_0[0])
    float gcur = __builtin_amdgcn_rcpf(RFL(u));
    float gE = gcur * __expf(emv(OBS[1], ea, eq, ec));

#pragma unroll 2
    for (int t = 1; t < SS; ++t) {
        // ---- 8 b128 reads of my source half (after prev write; in-order) ----
        const f4* Uq = (const f4*)U_lds + 8 * p;
        f4 U0 = Uq[0], U1 = Uq[1], U2 = Uq[2], U3 = Uq[3];
        f4 U4 = Uq[4], U5 = Uq[5], U6 = Uq[6], U7 = Uq[7];

        // ---- 32 pk ops: partials for outputs {e, e+1} over my 32 sources ----
        f2 aA0, aA1, aB0, aB1;
        PK_MUL(aA0, LO2(QA[0]), LO2(U0)); PK_MUL(aA1, HI2(QA[0]), HI2(U0));
        PK_MUL(aB0, LO2(QB[0]), LO2(U0)); PK_MUL(aB1, HI2(QB[0]), HI2(U0));
        PK_FMA(aA0, LO2(QA[1]), LO2(U1)); PK_FMA(aA1, HI2(QA[1]), HI2(U1));
        PK_FMA(aB0, LO2(QB[1]), LO2(U1)); PK_FMA(aB1, HI2(QB[1]), HI2(U1));
        PK_FMA(aA0, LO2(QA[2]), LO2(U2)); PK_FMA(aA1, HI2(QA[2]), HI2(U2));
        PK_FMA(aB0, LO2(QB[2]), LO2(U2)); PK_FMA(aB1, HI2(QB[2]), HI2(U2));
        PK_FMA(aA0, LO2(QA[3]), LO2(U3)); PK_FMA(aA1, HI2(QA[3]), HI2(U3));
        PK_FMA(aB0, LO2(QB[3]), LO2(U3)); PK_FMA(aB1, HI2(QB[3]), HI2(U3));
        PK_FMA(aA0, LO2(QA[4]), LO2(U4)); PK_FMA(aA1, HI2(QA[4]), HI2(U4));
        PK_FMA(aB0, LO2(QB[4]), LO2(U4)); PK_FMA(aB1, HI2(QB[4]), HI2(U4));
        PK_FMA(aA0, LO2(QA[5]), LO2(U5)); PK_FMA(aA1, HI2(QA[5]), HI2(U5));
        PK_FMA(aB0, LO2(QB[5]), LO2(U5)); PK_FMA(aB1, HI2(QB[5]), HI2(U5));
        PK_FMA(aA0, LO2(QA[6]), LO2(U6)); PK_FMA(aA1, HI2(QA[6]), HI2(U6));
        PK_FMA(aB0, LO2(QB[6]), LO2(U6)); PK_FMA(aB1, HI2(QB[6]), HI2(U6));
        PK_FMA(aA0, LO2(QA[7]), LO2(U7)); PK_FMA(aA1, HI2(QA[7]), HI2(U7));
        PK_FMA(aB0, LO2(QB[7]), LO2(U7)); PK_FMA(aB1, HI2(QB[7]), HI2(U7));

        f2 sA, sB;
        PK_ADD(sA, aA0, aA1);
        PK_ADD(sB, aB0, aB1);
        float s_e = sA.x + sA.y;   // partial of output e over my half
        float s_o = sB.x + sB.y;   // partial of output e+1 over my half
        // combine with partner lane (other source half): lane ^= 1
        DPP_X1_ADD(s_e);
        DPP_X1_ADD(s_o);
        const float sd = p ? s_o : s_e;  // my state's full dot
        const float un = sd * gE;        // gE ready since end of step t-1
        U_lds[l] = un;                   // write early: next iter's reads follow

        // ---- tail (off the next dot's critical path) ----
        lg = __logf(un);
        const float av = A + lg;
        alpha_b[(size_t)t * HH + l] = av;
        A = RFL(av);                                   // A_{t+1}
        gcur = __builtin_amdgcn_rcpf(RFL(un));         // next renorm scale
        const int tn = (t < SS - 1) ? t + 1 : SS - 1;
        const f4 xn = OBS[tn];
        gE = gcur * __expf(emv(xn, ea, eq, ec));       // next g*E
        u = un;
    }

    // log-likelihood: ll = A_{2047} + log(sum_j U_{2047}[j])
    float ssum = u;
    for (int d = 1; d < 64; d <<= 1) ssum += __shfl_xor(ssum, d, 64);
    const float lg0 = RFL(lg);  // log(U_{2047}[0]); A == A_{2047} + lg0
    if (l == 0) out[NT + b] = (A - lg0) + __logf(ssum);
}

extern "C" void kernel_launch(void* const* d_in, const int* in_sizes, int n_in,
                              void* d_out, int out_size, void* d_ws, size_t ws_size,
                              hipStream_t stream) {
    (void)in_sizes; (void)n_in; (void)out_size; (void)ws_size;
    const float* obs     = (const float*)d_in[0];
    const float* base    = (const float*)d_in[1];
    const float* init    = (const float*)d_in[2];
    const float* means   = (const float*)d_in[3];
    const float* logvars = (const float*)d_in[4];
    float* out = (float*)d_out;

    float* Qt = (float*)d_ws;                   // 16 KB
    float* D  = (float*)((char*)d_ws + 16384);  // 256 B

    hmm_setup<<<1, 64, 0, stream>>>(base, init, Qt, D);
    hmm_scan<<<BB, 64, 0, stream>>>(obs, means, logvars, Qt, D, out);
}

// Round 10
// 467.898 us; speedup vs baseline: 1.4072x; 1.0086x over previous
//
#include <hip/hip_runtime.h>
#include <math.h>

#define BB 128
#define SS 2048
#define HH 64
#define EPSQ 1e-10f
#define NT ((size_t)BB * SS * HH)

typedef float f2 __attribute__((ext_vector_type(2)));
typedef float f4 __attribute__((ext_vector_type(4)));

// ---- ws layout ----
// 0      : Qt[64][64]  Qt[j][i] = softmax(base)[i][j] + EPS  (transposed, 16 KB)
// 16384  : D[64]       softmax(init)+EPS                     (256 B)

__global__ __launch_bounds__(64) void hmm_setup(const float* __restrict__ base,
                                                const float* __restrict__ init,
                                                float* __restrict__ Qt,
                                                float* __restrict__ D) {
    const int i = threadIdx.x;  // 0..63 = source state (row of base)
    float mx = -INFINITY;
    for (int k = 0; k < HH; ++k) mx = fmaxf(mx, base[i * HH + k]);
    float z = 0.f;
    for (int k = 0; k < HH; ++k) z += expf(base[i * HH + k] - mx);
    float invz = 1.f / z;
    for (int k = 0; k < HH; ++k) Qt[k * HH + i] = expf(base[i * HH + k] - mx) * invz + EPSQ;
    float x = init[i];
    float m2 = x;
    for (int d = 1; d < 64; d <<= 1) m2 = fmaxf(m2, __shfl_xor(m2, d, 64));
    float e = expf(x - m2);
    float zz = e;
    for (int d = 1; d < 64; d <<= 1) zz += __shfl_xor(zz, d, 64);
    D[i] = e / zz + EPSQ;
}

// em(x) for a state: c0 + sum_c (a_c + q_c*x_c)*x_c
__device__ __forceinline__ float emv(const f4 x, const f4 a, const f4 q, float c0) {
    float em = c0;
    em = fmaf(fmaf(q.x, x.x, a.x), x.x, em);
    em = fmaf(fmaf(q.y, x.y, a.y), x.y, em);
    em = fmaf(fmaf(q.z, x.z, a.z), x.z, em);
    em = fmaf(fmaf(q.w, x.w, a.w), x.w, em);
    return em;
}

// Plain packed f32 ops (validated R5/R9). No op_sel (R7's failure mode).
#define PK_MUL(d, a, b) asm("v_pk_mul_f32 %0, %1, %2" : "=v"(d) : "v"(a), "v"(b))
#define PK_FMA(d, a, b) asm("v_pk_fma_f32 %0, %1, %2, %0" : "+v"(d) : "v"(a), "v"(b))
#define PK_ADD(d, a, b) asm("v_pk_add_f32 %0, %1, %2" : "=v"(d) : "v"(a), "v"(b))

// single-stage quad_perm [1,0,3,2] (lane ^= 1) add — validated R1/R9
#define DPP_X1_ADD(s)                                                                  \
    {                                                                                  \
        int _v = __builtin_amdgcn_mov_dpp(__float_as_int(s), 0xB1, 0xF, 0xF, true);    \
        s += __int_as_float(_v);                                                       \
    }

#define LO2(v) __builtin_shufflevector(v, v, 0, 1)
#define HI2(v) __builtin_shufflevector(v, v, 2, 3)

#define RFL(x) __int_as_float(__builtin_amdgcn_readfirstlane(__float_as_int(x)))

// One wave per batch; lane l owns state l. Pair-split dot (R9, validated):
// parity p = l&1 selects source half [32p, 32p+32); lane computes partials for
// both outputs of its pair {e, e+1} over its half (32 pk ops = the floor),
// one DPP xor-1 add combines. NEW in R10: software-pipelined U reads — after
// ds_write of un, the NEXT step's 16 ds_read_b64 are issued immediately
// (in-order DS => they see the write), and their latency is hidden under the
// tail VALU (log, alpha store, renorm rcp, emission exp). U is read directly
// as f2 to avoid f4->f2 extraction movs in the asm operands.
__global__ __launch_bounds__(64, 1) void hmm_scan(const float* __restrict__ obs,
                                                  const float* __restrict__ means,
                                                  const float* __restrict__ logvars,
                                                  const float* __restrict__ Qt,
                                                  const float* __restrict__ D,
                                                  float* __restrict__ out) {
    const int b = blockIdx.x;
    const int l = threadIdx.x;  // 0..63 = state
    const int p = l & 1;        // source-half parity
    const int e = l & ~1;       // even output of my pair

    __shared__ f4 OBS[SS];       // 32 KB
    __shared__ float U_lds[HH];  // 256 B, single buffer (in-order DS)

    // stage obs (coalesced b128; single wave => no barrier)
    const f4* obs4 = (const f4*)obs + (size_t)b * SS;
#pragma unroll 8
    for (int t = l; t < SS; t += 64) OBS[t] = obs4[t];

    // Q fragments pre-split to f2 (prologue-only; 32+32 f2 = 64 VGPRs):
    // QA2[m] = {Qt[e][32p+2m], Qt[e][32p+2m+1]}, QB2 likewise for e+1.
    f2 QA2[16], QB2[16];
    {
        const f4* qa = (const f4*)(Qt + (size_t)e * HH + 32 * p);
        const f4* qb = (const f4*)(Qt + (size_t)(e + 1) * HH + 32 * p);
#pragma unroll
        for (int k = 0; k < 8; ++k) {
            f4 va = qa[k], vb = qb[k];
            QA2[2 * k] = LO2(va); QA2[2 * k + 1] = HI2(va);
            QB2[2 * k] = LO2(vb); QB2[2 * k + 1] = HI2(vb);
        }
    }

    // emission constants for state l
    const f4 mu = ((const f4*)means)[l];
    const f4 lv = ((const f4*)logvars)[l];
    f4 ea, eq;
    float ec = 0.f;
    {
        float v0 = __expf(lv.x) + 1e-6f, v1 = __expf(lv.y) + 1e-6f;
        float v2 = __expf(lv.z) + 1e-6f, v3 = __expf(lv.w) + 1e-6f;
        float i0 = 1.f / v0, i1 = 1.f / v1, i2 = 1.f / v2, i3 = 1.f / v3;
        ea.x = mu.x * i0; ea.y = mu.y * i1; ea.z = mu.z * i2; ea.w = mu.w * i3;
        eq.x = -0.5f * i0; eq.y = -0.5f * i1; eq.z = -0.5f * i2; eq.w = -0.5f * i3;
        ec += logf(6.2831853071795864f * v0) + mu.x * mu.x * i0;
        ec += logf(6.2831853071795864f * v1) + mu.y * mu.y * i1;
        ec += logf(6.2831853071795864f * v2) + mu.z * mu.z * i2;
        ec += logf(6.2831853071795864f * v3) + mu.w * mu.w * i3;
        ec = -0.5f * ec;
    }

    float* alpha_b = out + (size_t)b * SS * HH;

    // ---- t = 0 (prologue of the pipeline) ----
    float u = D[l] * __expf(emv(OBS[0], ea, eq, ec));
    U_lds[l] = u;                    // ds_write
    // issue the t=1 source reads right after the write (in-order DS)
    const f2* Up2 = (const f2*)U_lds + 16 * p;  // my half as 16 f2
    f2 Ur[16];
#pragma unroll
    for (int m = 0; m < 16; ++m) Ur[m] = Up2[m];

    float lg = __logf(u);
    alpha_b[l] = lg;                 // A_0 = 0
    float A = RFL(lg);               // = A_1 = log(U_0[0])
    float gcur = __builtin_amdgcn_rcpf(RFL(u));
    float gE = gcur * __expf(emv(OBS[1], ea, eq, ec));

    float un = u;
#pragma unroll 2
    for (int t = 1; t < SS; ++t) {
        // ---- dot over the pipelined registers (wait inserted by compiler) ----
        f2 aA0, aA1, aB0, aB1;
        PK_MUL(aA0, QA2[0], Ur[0]);  PK_MUL(aB0, QB2[0], Ur[0]);
        PK_MUL(aA1, QA2[1], Ur[1]);  PK_MUL(aB1, QB2[1], Ur[1]);
        PK_FMA(aA0, QA2[2], Ur[2]);  PK_FMA(aB0, QB2[2], Ur[2]);
        PK_FMA(aA1, QA2[3], Ur[3]);  PK_FMA(aB1, QB2[3], Ur[3]);
        PK_FMA(aA0, QA2[4], Ur[4]);  PK_FMA(aB0, QB2[4], Ur[4]);
        PK_FMA(aA1, QA2[5], Ur[5]);  PK_FMA(aB1, QB2[5], Ur[5]);
        PK_FMA(aA0, QA2[6], Ur[6]);  PK_FMA(aB0, QB2[6], Ur[6]);
        PK_FMA(aA1, QA2[7], Ur[7]);  PK_FMA(aB1, QB2[7], Ur[7]);
        PK_FMA(aA0, QA2[8], Ur[8]);  PK_FMA(aB0, QB2[8], Ur[8]);
        PK_FMA(aA1, QA2[9], Ur[9]);  PK_FMA(aB1, QB2[9], Ur[9]);
        PK_FMA(aA0, QA2[10], Ur[10]); PK_FMA(aB0, QB2[10], Ur[10]);
        PK_FMA(aA1, QA2[11], Ur[11]); PK_FMA(aB1, QB2[11], Ur[11]);
        PK_FMA(aA0, QA2[12], Ur[12]); PK_FMA(aB0, QB2[12], Ur[12]);
        PK_FMA(aA1, QA2[13], Ur[13]); PK_FMA(aB1, QB2[13], Ur[13]);
        PK_FMA(aA0, QA2[14], Ur[14]); PK_FMA(aB0, QB2[14], Ur[14]);
        PK_FMA(aA1, QA2[15], Ur[15]); PK_FMA(aB1, QB2[15], Ur[15]);

        f2 sA, sB;
        PK_ADD(sA, aA0, aA1);
        PK_ADD(sB, aB0, aB1);
        float s_e = sA.x + sA.y;   // partial of output e over my half
        float s_o = sB.x + sB.y;   // partial of output e+1 over my half
        DPP_X1_ADD(s_e);           // + partner (other half)
        DPP_X1_ADD(s_o);
        const float sd = p ? s_o : s_e;  // my state's full dot
        un = sd * gE;                    // gE ready since end of step t-1

        // ---- write, then immediately issue NEXT step's reads (in-order) ----
        U_lds[l] = un;
#pragma unroll
        for (int m = 0; m < 16; ++m) Ur[m] = Up2[m];
        const int tn = (t < SS - 1) ? t + 1 : SS - 1;
        const f4 xn = OBS[tn];           // DS read, consumer late

        // ---- tail VALU: hides the DS latency just issued ----
        lg = __logf(un);
        const float av = A + lg;
        alpha_b[(size_t)t * HH + l] = av;
        A = RFL(av);                                   // A_{t+1}
        gcur = __builtin_amdgcn_rcpf(RFL(un));         // next renorm scale
        gE = gcur * __expf(emv(xn, ea, eq, ec));       // next g*E
    }

    // log-likelihood: ll = A_{2047} + log(sum_j U_{2047}[j])
    float ssum = un;
    for (int d = 1; d < 64; d <<= 1) ssum += __shfl_xor(ssum, d, 64);
    const float lg0 = RFL(lg);  // log(U_{2047}[0]); A == A_{2047} + lg0
    if (l == 0) out[NT + b] = (A - lg0) + __logf(ssum);
}

extern "C" void kernel_launch(void* const* d_in, const int* in_sizes, int n_in,
                              void* d_out, int out_size, void* d_ws, size_t ws_size,
                              hipStream_t stream) {
    (void)in_sizes; (void)n_in; (void)out_size; (void)ws_size;
    const float* obs     = (const float*)d_in[0];
    const float* base    = (const float*)d_in[1];
    const float* init    = (const float*)d_in[2];
    const float* means   = (const float*)d_in[3];
    const float* logvars = (const float*)d_in[4];
    float* out = (float*)d_out;

    float* Qt = (float*)d_ws;                   // 16 KB
    float* D  = (float*)((char*)d_ws + 16384);  // 256 B

    hmm_setup<<<1, 64, 0, stream>>>(base, init, Qt, D);
    hmm_scan<<<BB, 64, 0, stream>>>(obs, means, logvars, Qt, D, out);
}